// Round 2
// baseline (237.985 us; speedup 1.0000x reference)
//
#include <hip/hip_runtime.h>

#define B_ 128
#define T_ 256
#define C_ 512
#define H_ 512
// softmax scale * log2(e):  (1/sqrt(512)) * 1.44269504
#define CSCALE 0.063763824f

typedef _Float16 f16x8 __attribute__((ext_vector_type(8)));
typedef _Float16 f16x4 __attribute__((ext_vector_type(4)));
typedef float    f32x4 __attribute__((ext_vector_type(4)));

// async global->LDS, 16B per lane; LDS dest must be wave-uniform base (+lane*16)
__device__ __forceinline__ void gld16(const void* gsrc, void* ldst) {
  __builtin_amdgcn_global_load_lds(
      (__attribute__((address_space(1))) void*)gsrc,
      (__attribute__((address_space(3))) void*)ldst, 16, 0, 0);
}

// ---------------------------------------------------------------- convert
__global__ __launch_bounds__(256) void cvt_kernel(
    const float4* __restrict__ x, const float4* __restrict__ wq,
    const float4* __restrict__ wk, const float4* __restrict__ wv,
    f16x4* __restrict__ dst) {
  const int NX = (B_ * T_ * C_) / 4;   // 4,194,304
  const int NW = (H_ * C_) / 4;        // 65,536
  const int total = NX + 3 * NW;
  int gid = blockIdx.x * 256 + threadIdx.x;
  int gsz = gridDim.x * 256;
  for (int i = gid; i < total; i += gsz) {
    float4 f;
    if (i < NX)            f = x[i];
    else if (i < NX + NW)  f = wq[i - NX];
    else if (i < NX + 2*NW) f = wk[i - NX - NW];
    else                   f = wv[i - NX - 2*NW];
    f16x4 u = {(_Float16)f.x, (_Float16)f.y, (_Float16)f.z, (_Float16)f.w};
    dst[i] = u;
  }
}

// ---------------------------------------------------------------- QKV proj
// gemm_bt: out[m][n] = sum_k A[m][k] * W[n][k];  m97 structure (128x128, BK=32)
// z=0 -> q [B*T, H]; z=1 -> k [B*T, H]; z=2 -> v^T [B, H, T]
__global__ __launch_bounds__(256) void proj_kernel(
    const _Float16* __restrict__ xh, const _Float16* __restrict__ wh,
    _Float16* __restrict__ qh, _Float16* __restrict__ kh,
    _Float16* __restrict__ vth) {
  __shared__ _Float16 As[128 * 32];  // 8 KB, row-major [128][32]
  __shared__ _Float16 Bs[128 * 32];  // 8 KB

  const int tid  = threadIdx.x;
  const int lane = tid & 63;
  const int wave = tid >> 6;
  const int lr = lane & 15, lk = lane >> 4;
  const int m0 = blockIdx.x * 128;
  const int n0 = blockIdx.y * 128;
  const int z  = blockIdx.z;
  const _Float16* wz = wh + z * (H_ * C_);

  const int wm = (wave >> 1) * 64;
  const int wn = (wave & 1) * 64;

  f32x4 acc[4][4];
#pragma unroll
  for (int i = 0; i < 4; ++i)
#pragma unroll
    for (int j = 0; j < 4; ++j) acc[i][j] = {0.f, 0.f, 0.f, 0.f};

  // staging: thread t covers row = i*64 + (t>>2), col = (t&3)*8 (8 f16 = 16B)
  const int srow = tid >> 2, scol = (tid & 3) * 8;
  const _Float16* aSrc = xh + (m0 + srow) * C_ + scol;
  const _Float16* bSrc = wz + (n0 + srow) * C_ + scol;

  for (int k0 = 0; k0 < C_; k0 += 32) {
    __syncthreads();  // previous compute done reading LDS
#pragma unroll
    for (int i = 0; i < 2; ++i) {
      gld16((const void*)(aSrc + i * 64 * C_ + k0), (void*)&As[i * 2048 + wave * 512]);
      gld16((const void*)(bSrc + i * 64 * C_ + k0), (void*)&Bs[i * 2048 + wave * 512]);
    }
    __syncthreads();  // staging drained (vmcnt(0) at barrier)

    f16x8 a[4], b[4];
#pragma unroll
    for (int mi = 0; mi < 4; ++mi)
      a[mi] = *(const f16x8*)&As[(wm + mi * 16 + lr) * 32 + lk * 8];
#pragma unroll
    for (int ni = 0; ni < 4; ++ni)
      b[ni] = *(const f16x8*)&Bs[(wn + ni * 16 + lr) * 32 + lk * 8];
#pragma unroll
    for (int mi = 0; mi < 4; ++mi)
#pragma unroll
      for (int ni = 0; ni < 4; ++ni)
        acc[mi][ni] = __builtin_amdgcn_mfma_f32_16x16x32_f16(a[mi], b[ni], acc[mi][ni], 0, 0, 0);
  }

  // epilogue. D layout: col = lane&15, row = (lane>>4)*4 + r   [measured m89/m91]
  if (z < 2) {
    _Float16* out = (z == 0) ? qh : kh;
#pragma unroll
    for (int mi = 0; mi < 4; ++mi) {
      int mbase = m0 + wm + mi * 16 + lk * 4;
#pragma unroll
      for (int ni = 0; ni < 4; ++ni) {
        int n = n0 + wn + ni * 16 + lr;
#pragma unroll
        for (int r = 0; r < 4; ++r)
          out[(mbase + r) * H_ + n] = (_Float16)acc[mi][ni][r];
      }
    }
  } else {
    // v^T[b][h][t]; r=0..3 are consecutive t -> pack 8B store
#pragma unroll
    for (int mi = 0; mi < 4; ++mi) {
      int mbase = m0 + wm + mi * 16 + lk * 4;
      int bb = mbase >> 8, tt = mbase & 255;
#pragma unroll
      for (int ni = 0; ni < 4; ++ni) {
        int n = n0 + wn + ni * 16 + lr;
        f16x4 u = {(_Float16)acc[mi][ni][0], (_Float16)acc[mi][ni][1],
                   (_Float16)acc[mi][ni][2], (_Float16)acc[mi][ni][3]};
        *(f16x4*)&vth[bb * (H_ * T_) + n * T_ + tt] = u;
      }
    }
  }
}

// ---------------------------------------------------------------- attention
// Wave-independent flash attention, NO K/V LDS staging, NO barriers.
// Each wave owns 16 q-rows. Block = 2 paired waves (qw, 15-qw) -> every
// block does exactly 9 kv-iterations (perfect balance). Grid (8, 128).
// K fragments: 16B-contiguous in kh (row-major H). V fragments:
// 16B-contiguous in vth ([B,H,T] K-major). Both L1/L2-resident (512KB/batch).
// LDS: only per-wave P-transpose scratch, stride 40 f16 (conflict-free).
__global__ __launch_bounds__(128) void attn_kernel(
    const _Float16* __restrict__ qh, const _Float16* __restrict__ kh,
    const _Float16* __restrict__ vth, float* __restrict__ dout) {
  __shared__ _Float16 Ps[2 * 16 * 40];  // 2 waves x [16 q][40 stride]

  const int tid  = threadIdx.x;
  const int lane = tid & 63;
  const int wq   = tid >> 6;           // 0..1
  const int lr = lane & 15, lk = lane >> 4;
  const int p  = blockIdx.x;           // 0..7
  const int b  = blockIdx.y;           // 0..127
  const int qw = wq ? (15 - p) : p;    // paired: work = (p>>1)+( (15-p)>>1 )+2 = 9
  const int q0 = qw * 16;
  const int nkv = (qw >> 1) + 1;       // kv tiles of 32

  // hoist Q fragments: A-frag row = lr, k covered by (f, lk)
  f16x8 qf[16];
  const _Float16* qrow = qh + ((size_t)b * T_ + q0 + lr) * H_;
#pragma unroll
  for (int f = 0; f < 16; ++f) qf[f] = *(const f16x8*)&qrow[f * 32 + lk * 8];

  f32x4 o[32];
#pragma unroll
  for (int i = 0; i < 32; ++i) o[i] = {0.f, 0.f, 0.f, 0.f};
  float m[4], l[4];
#pragma unroll
  for (int r = 0; r < 4; ++r) { m[r] = -1e30f; l[r] = 0.f; }

  const _Float16* kbase = kh + (size_t)b * T_ * H_;
  const _Float16* vbase = vth + (size_t)b * H_ * T_;
  _Float16* Pw = &Ps[wq * 640];

  for (int kvt = 0; kvt < nkv; ++kvt) {
    const int kv0 = kvt * 32;

    // ---- QK^T: S[16q x 32kv], K-dim = H = 512; 4 indep accumulator chains
    f32x4 s0 = {0.f, 0.f, 0.f, 0.f}, s1 = {0.f, 0.f, 0.f, 0.f};
    f32x4 t0 = {0.f, 0.f, 0.f, 0.f}, t1 = {0.f, 0.f, 0.f, 0.f};
    const _Float16* krow0 = kbase + (size_t)(kv0 + lr) * H_ + lk * 8;
    const _Float16* krow1 = krow0 + 16 * H_;
#pragma unroll
    for (int ks = 0; ks < 16; ks += 2) {
      f16x8 b0 = *(const f16x8*)&krow0[ks * 32];
      f16x8 b1 = *(const f16x8*)&krow1[ks * 32];
      f16x8 c0 = *(const f16x8*)&krow0[ks * 32 + 32];
      f16x8 c1 = *(const f16x8*)&krow1[ks * 32 + 32];
      s0 = __builtin_amdgcn_mfma_f32_16x16x32_f16(qf[ks], b0, s0, 0, 0, 0);
      s1 = __builtin_amdgcn_mfma_f32_16x16x32_f16(qf[ks], b1, s1, 0, 0, 0);
      t0 = __builtin_amdgcn_mfma_f32_16x16x32_f16(qf[ks + 1], c0, t0, 0, 0, 0);
      t1 = __builtin_amdgcn_mfma_f32_16x16x32_f16(qf[ks + 1], c1, t1, 0, 0, 0);
    }
    s0 = s0 + t0;
    s1 = s1 + t1;

    // ---- causal mask + row max (rows live in (lk, r); cols across lr)
    float p0[4], p1[4], rm[4];
    const int rowb = q0 + lk * 4;
#pragma unroll
    for (int r = 0; r < 4; ++r) {
      float v0 = (kv0 + lr      > rowb + r) ? -1e30f : s0[r];
      float v1 = (kv0 + 16 + lr > rowb + r) ? -1e30f : s1[r];
      s0[r] = v0; s1[r] = v1;
      rm[r] = fmaxf(v0, v1);
    }
#pragma unroll
    for (int off = 1; off < 16; off <<= 1)
#pragma unroll
      for (int r = 0; r < 4; ++r) rm[r] = fmaxf(rm[r], __shfl_xor(rm[r], off, 64));

    // ---- defer-max (T13): only rescale when max grew > 64 raw (~e^4 headroom)
    bool need = false;
#pragma unroll
    for (int r = 0; r < 4; ++r) need = need || (rm[r] > m[r] + 64.f);
    if (__any(need)) {
#pragma unroll
      for (int r = 0; r < 4; ++r) {
        float mn = fmaxf(m[r], rm[r]);
        float al = __builtin_amdgcn_exp2f((m[r] - mn) * CSCALE);
        m[r] = mn; l[r] *= al;
#pragma unroll
        for (int hf = 0; hf < 32; ++hf) o[hf][r] *= al;
      }
    }

    float rs[4];
#pragma unroll
    for (int r = 0; r < 4; ++r) {
      p0[r] = __builtin_amdgcn_exp2f((s0[r] - m[r]) * CSCALE);
      p1[r] = __builtin_amdgcn_exp2f((s1[r] - m[r]) * CSCALE);
      rs[r] = p0[r] + p1[r];
    }
#pragma unroll
    for (int off = 1; off < 16; off <<= 1)
#pragma unroll
      for (int r = 0; r < 4; ++r) rs[r] += __shfl_xor(rs[r], off, 64);
#pragma unroll
    for (int r = 0; r < 4; ++r) l[r] += rs[r];

    // ---- P transpose through per-wave LDS scratch (wave-private, no barrier)
    // write: row = lk*4+r, col = lr / lr+16; stride 40 f16 -> 2-way max (free)
#pragma unroll
    for (int r = 0; r < 4; ++r) {
      Pw[(lk * 4 + r) * 40 + lr]      = (_Float16)p0[r];
      Pw[(lk * 4 + r) * 40 + 16 + lr] = (_Float16)p1[r];
    }
    f16x8 pa = *(const f16x8*)&Pw[lr * 40 + lk * 8];  // A-frag: row=lr, k=lk*8+j

    // ---- PV: o[16q x 512h] += P[16x32] * V[32x512]; V direct from global
    const _Float16* vcol = vbase + (size_t)lr * T_ + kv0 + lk * 8;
#pragma unroll
    for (int hf = 0; hf < 32; ++hf) {
      f16x8 vb = *(const f16x8*)&vcol[(size_t)hf * 16 * T_];
      o[hf] = __builtin_amdgcn_mfma_f32_16x16x32_f16(pa, vb, o[hf], 0, 0, 0);
    }
  }

  // ---- normalize + store fp32
  float linv[4];
#pragma unroll
  for (int r = 0; r < 4; ++r) linv[r] = 1.0f / l[r];
  float* orow = dout + ((size_t)b * T_ + q0 + lk * 4) * H_;
#pragma unroll
  for (int hf = 0; hf < 32; ++hf)
#pragma unroll
    for (int r = 0; r < 4; ++r)
      orow[(size_t)r * H_ + hf * 16 + lr] = o[hf][r] * linv[r];
}

// ---------------------------------------------------------------- launch
extern "C" void kernel_launch(void* const* d_in, const int* in_sizes, int n_in,
                              void* d_out, int out_size, void* d_ws, size_t ws_size,
                              hipStream_t stream) {
  const size_t NXE = (size_t)B_ * T_ * C_;   // 16,777,216
  const size_t NWE = (size_t)3 * H_ * C_;    // 786,432
  const size_t NQE = (size_t)B_ * T_ * H_;   // 16,777,216
  const size_t need = (NXE + NWE + 3 * NQE) * sizeof(_Float16);  // 135,790,592 B
  if (ws_size < need) return;  // loud failure (absmax = max|ref|) -> ws too small

  const float* x  = (const float*)d_in[0];
  const float* wq = (const float*)d_in[1];
  const float* wk = (const float*)d_in[2];
  const float* wv = (const float*)d_in[3];

  _Float16* xh  = (_Float16*)d_ws;
  _Float16* wh  = xh + NXE;
  _Float16* qh  = wh + NWE;
  _Float16* kh  = qh + NQE;
  _Float16* vth = kh + NQE;

  cvt_kernel<<<2048, 256, 0, stream>>>((const float4*)x, (const float4*)wq,
                                       (const float4*)wk, (const float4*)wv,
                                       (f16x4*)xh);
  proj_kernel<<<dim3(256, 4, 3), dim3(256), 0, stream>>>(xh, wh, qh, kh, vth);
  attn_kernel<<<dim3(8, 128), dim3(128), 0, stream>>>(qh, kh, vth, (float*)d_out);
}

// Round 3
// 202.217 us; speedup vs baseline: 1.1769x; 1.1769x over previous
//
#include <hip/hip_runtime.h>

#define B_ 128
#define T_ 256
#define C_ 512
#define H_ 512
// softmax scale * log2(e):  (1/sqrt(512)) * 1.44269504
#define CSCALE 0.063763824f

typedef _Float16 f16x8 __attribute__((ext_vector_type(8)));
typedef _Float16 f16x4 __attribute__((ext_vector_type(4)));
typedef float    f32x4 __attribute__((ext_vector_type(4)));

// async global->LDS, 16B per lane; LDS dest must be wave-uniform base (+lane*16)
__device__ __forceinline__ void gld16(const void* gsrc, void* ldst) {
  __builtin_amdgcn_global_load_lds(
      (__attribute__((address_space(1))) void*)gsrc,
      (__attribute__((address_space(3))) void*)ldst, 16, 0, 0);
}

// ---------------------------------------------------------------- convert
__global__ __launch_bounds__(256) void cvt_kernel(
    const float4* __restrict__ x, const float4* __restrict__ wq,
    const float4* __restrict__ wk, const float4* __restrict__ wv,
    f16x4* __restrict__ dst) {
  const int NX = (B_ * T_ * C_) / 4;   // 4,194,304
  const int NW = (H_ * C_) / 4;        // 65,536
  const int total = NX + 3 * NW;
  int gid = blockIdx.x * 256 + threadIdx.x;
  int gsz = gridDim.x * 256;
  for (int i = gid; i < total; i += gsz) {
    float4 f;
    if (i < NX)            f = x[i];
    else if (i < NX + NW)  f = wq[i - NX];
    else if (i < NX + 2*NW) f = wk[i - NX - NW];
    else                   f = wv[i - NX - 2*NW];
    f16x4 u = {(_Float16)f.x, (_Float16)f.y, (_Float16)f.z, (_Float16)f.w};
    dst[i] = u;
  }
}

// ---------------------------------------------------------------- QKV proj
// gemm_bt: out[m][n] = sum_k A[m][k] * W[n][k];  m97 structure (128x128, BK=32)
// z=0 -> q [B*T, H]; z=1 -> k [B*T, H]; z=2 -> v^T [B, H, T]
__global__ __launch_bounds__(256) void proj_kernel(
    const _Float16* __restrict__ xh, const _Float16* __restrict__ wh,
    _Float16* __restrict__ qh, _Float16* __restrict__ kh,
    _Float16* __restrict__ vth) {
  __shared__ _Float16 As[128 * 32];  // 8 KB, row-major [128][32]
  __shared__ _Float16 Bs[128 * 32];  // 8 KB

  const int tid  = threadIdx.x;
  const int lane = tid & 63;
  const int wave = tid >> 6;
  const int lr = lane & 15, lk = lane >> 4;
  const int m0 = blockIdx.x * 128;
  const int n0 = blockIdx.y * 128;
  const int z  = blockIdx.z;
  const _Float16* wz = wh + z * (H_ * C_);

  const int wm = (wave >> 1) * 64;
  const int wn = (wave & 1) * 64;

  f32x4 acc[4][4];
#pragma unroll
  for (int i = 0; i < 4; ++i)
#pragma unroll
    for (int j = 0; j < 4; ++j) acc[i][j] = {0.f, 0.f, 0.f, 0.f};

  // staging: thread t covers row = i*64 + (t>>2), col = (t&3)*8 (8 f16 = 16B)
  const int srow = tid >> 2, scol = (tid & 3) * 8;
  const _Float16* aSrc = xh + (m0 + srow) * C_ + scol;
  const _Float16* bSrc = wz + (n0 + srow) * C_ + scol;

  for (int k0 = 0; k0 < C_; k0 += 32) {
    __syncthreads();  // previous compute done reading LDS
#pragma unroll
    for (int i = 0; i < 2; ++i) {
      gld16((const void*)(aSrc + i * 64 * C_ + k0), (void*)&As[i * 2048 + wave * 512]);
      gld16((const void*)(bSrc + i * 64 * C_ + k0), (void*)&Bs[i * 2048 + wave * 512]);
    }
    __syncthreads();  // staging drained (vmcnt(0) at barrier)

    f16x8 a[4], b[4];
#pragma unroll
    for (int mi = 0; mi < 4; ++mi)
      a[mi] = *(const f16x8*)&As[(wm + mi * 16 + lr) * 32 + lk * 8];
#pragma unroll
    for (int ni = 0; ni < 4; ++ni)
      b[ni] = *(const f16x8*)&Bs[(wn + ni * 16 + lr) * 32 + lk * 8];
#pragma unroll
    for (int mi = 0; mi < 4; ++mi)
#pragma unroll
      for (int ni = 0; ni < 4; ++ni)
        acc[mi][ni] = __builtin_amdgcn_mfma_f32_16x16x32_f16(a[mi], b[ni], acc[mi][ni], 0, 0, 0);
  }

  // epilogue. D layout: col = lane&15, row = (lane>>4)*4 + r   [measured m89/m91]
  if (z < 2) {
    _Float16* out = (z == 0) ? qh : kh;
#pragma unroll
    for (int mi = 0; mi < 4; ++mi) {
      int mbase = m0 + wm + mi * 16 + lk * 4;
#pragma unroll
      for (int ni = 0; ni < 4; ++ni) {
        int n = n0 + wn + ni * 16 + lr;
#pragma unroll
        for (int r = 0; r < 4; ++r)
          out[(mbase + r) * H_ + n] = (_Float16)acc[mi][ni][r];
      }
    }
  } else {
    // v^T[b][h][t]; r=0..3 are consecutive t -> pack 8B store
#pragma unroll
    for (int mi = 0; mi < 4; ++mi) {
      int mbase = m0 + wm + mi * 16 + lk * 4;
      int bb = mbase >> 8, tt = mbase & 255;
#pragma unroll
      for (int ni = 0; ni < 4; ++ni) {
        int n = n0 + wn + ni * 16 + lr;
        f16x4 u = {(_Float16)acc[mi][ni][0], (_Float16)acc[mi][ni][1],
                   (_Float16)acc[mi][ni][2], (_Float16)acc[mi][ni][3]};
        *(f16x4*)&vth[bb * (H_ * T_) + n * T_ + tt] = u;
      }
    }
  }
}

// ---------------------------------------------------------------- attention
// Wave-independent flash attention, direct-global K/V fragments, no barriers.
// Block = 2 paired waves (qw, 15-qw) -> every block does exactly 9 kv-iters.
// XCD-LOCALITY SWIZZLE (T1): flat grid 1024; flat = (b&7) + 8*(p + 8*(b>>3))
// -> all 8 blocks of batch b satisfy flat % 8 == b % 8 -> SAME XCD L2 ->
// K/V (512KB/batch) fetched from HBM once per batch, not once per XCD.
__global__ __launch_bounds__(128) void attn_kernel(
    const _Float16* __restrict__ qh, const _Float16* __restrict__ kh,
    const _Float16* __restrict__ vth, float* __restrict__ dout) {
  __shared__ _Float16 Ps[2 * 16 * 40];  // 2 waves x [16 q][40 stride]

  const int tid  = threadIdx.x;
  const int lane = tid & 63;
  const int wq   = tid >> 6;           // 0..1
  const int lr = lane & 15, lk = lane >> 4;
  const int flat = blockIdx.x;         // 0..1023
  const int xcd  = flat & 7;
  const int rest = flat >> 3;
  const int p    = rest & 7;           // q-pair index 0..7
  const int g    = rest >> 3;          // 0..15
  const int b    = xcd + (g << 3);     // batch 0..127, pinned to XCD (b&7)
  const int qw = wq ? (15 - p) : p;    // paired: work = 9 kv-iters per block
  const int q0 = qw * 16;
  const int nkv = (qw >> 1) + 1;       // kv tiles of 32

  // hoist Q fragments: A-frag row = lr, k covered by (f, lk)
  f16x8 qf[16];
  const _Float16* qrow = qh + ((size_t)b * T_ + q0 + lr) * H_;
#pragma unroll
  for (int f = 0; f < 16; ++f) qf[f] = *(const f16x8*)&qrow[f * 32 + lk * 8];

  f32x4 o[32];
#pragma unroll
  for (int i = 0; i < 32; ++i) o[i] = {0.f, 0.f, 0.f, 0.f};
  float m[4], l[4];
#pragma unroll
  for (int r = 0; r < 4; ++r) { m[r] = -1e30f; l[r] = 0.f; }

  const _Float16* kbase = kh + (size_t)b * T_ * H_;
  const _Float16* vbase = vth + (size_t)b * H_ * T_;
  _Float16* Pw = &Ps[wq * 640];

  for (int kvt = 0; kvt < nkv; ++kvt) {
    const int kv0 = kvt * 32;

    // ---- QK^T: S[16q x 32kv], K-dim = H = 512; 4 indep accumulator chains
    f32x4 s0 = {0.f, 0.f, 0.f, 0.f}, s1 = {0.f, 0.f, 0.f, 0.f};
    f32x4 t0 = {0.f, 0.f, 0.f, 0.f}, t1 = {0.f, 0.f, 0.f, 0.f};
    const _Float16* krow0 = kbase + (size_t)(kv0 + lr) * H_ + lk * 8;
    const _Float16* krow1 = krow0 + 16 * H_;
#pragma unroll
    for (int ks = 0; ks < 16; ks += 2) {
      f16x8 b0 = *(const f16x8*)&krow0[ks * 32];
      f16x8 b1 = *(const f16x8*)&krow1[ks * 32];
      f16x8 c0 = *(const f16x8*)&krow0[ks * 32 + 32];
      f16x8 c1 = *(const f16x8*)&krow1[ks * 32 + 32];
      s0 = __builtin_amdgcn_mfma_f32_16x16x32_f16(qf[ks], b0, s0, 0, 0, 0);
      s1 = __builtin_amdgcn_mfma_f32_16x16x32_f16(qf[ks], b1, s1, 0, 0, 0);
      t0 = __builtin_amdgcn_mfma_f32_16x16x32_f16(qf[ks + 1], c0, t0, 0, 0, 0);
      t1 = __builtin_amdgcn_mfma_f32_16x16x32_f16(qf[ks + 1], c1, t1, 0, 0, 0);
    }
    s0 = s0 + t0;
    s1 = s1 + t1;

    // ---- causal mask + row max (rows live in (lk, r); cols across lr)
    float p0[4], p1[4], rm[4];
    const int rowb = q0 + lk * 4;
#pragma unroll
    for (int r = 0; r < 4; ++r) {
      float v0 = (kv0 + lr      > rowb + r) ? -1e30f : s0[r];
      float v1 = (kv0 + 16 + lr > rowb + r) ? -1e30f : s1[r];
      s0[r] = v0; s1[r] = v1;
      rm[r] = fmaxf(v0, v1);
    }
#pragma unroll
    for (int off = 1; off < 16; off <<= 1)
#pragma unroll
      for (int r = 0; r < 4; ++r) rm[r] = fmaxf(rm[r], __shfl_xor(rm[r], off, 64));

    // ---- defer-max (T13): only rescale when max grew > 64 raw (~e^4 headroom)
    bool need = false;
#pragma unroll
    for (int r = 0; r < 4; ++r) need = need || (rm[r] > m[r] + 64.f);
    if (__any(need)) {
#pragma unroll
      for (int r = 0; r < 4; ++r) {
        float mn = fmaxf(m[r], rm[r]);
        float al = __builtin_amdgcn_exp2f((m[r] - mn) * CSCALE);
        m[r] = mn; l[r] *= al;
#pragma unroll
        for (int hf = 0; hf < 32; ++hf) o[hf][r] *= al;
      }
    }

    float rs[4];
#pragma unroll
    for (int r = 0; r < 4; ++r) {
      p0[r] = __builtin_amdgcn_exp2f((s0[r] - m[r]) * CSCALE);
      p1[r] = __builtin_amdgcn_exp2f((s1[r] - m[r]) * CSCALE);
      rs[r] = p0[r] + p1[r];
    }
#pragma unroll
    for (int off = 1; off < 16; off <<= 1)
#pragma unroll
      for (int r = 0; r < 4; ++r) rs[r] += __shfl_xor(rs[r], off, 64);
#pragma unroll
    for (int r = 0; r < 4; ++r) l[r] += rs[r];

    // ---- P transpose through per-wave LDS scratch (wave-private, no barrier)
    // write: row = lk*4+r, col = lr / lr+16; stride 40 f16 -> 2-way max (free)
#pragma unroll
    for (int r = 0; r < 4; ++r) {
      Pw[(lk * 4 + r) * 40 + lr]      = (_Float16)p0[r];
      Pw[(lk * 4 + r) * 40 + 16 + lr] = (_Float16)p1[r];
    }
    f16x8 pa = *(const f16x8*)&Pw[lr * 40 + lk * 8];  // A-frag: row=lr, k=lk*8+j

    // ---- PV: o[16q x 512h] += P[16x32] * V[32x512]; V direct from global
    const _Float16* vcol = vbase + (size_t)lr * T_ + kv0 + lk * 8;
#pragma unroll
    for (int hf = 0; hf < 32; ++hf) {
      f16x8 vb = *(const f16x8*)&vcol[(size_t)hf * 16 * T_];
      o[hf] = __builtin_amdgcn_mfma_f32_16x16x32_f16(pa, vb, o[hf], 0, 0, 0);
    }
  }

  // ---- normalize + store fp32
  float linv[4];
#pragma unroll
  for (int r = 0; r < 4; ++r) linv[r] = 1.0f / l[r];
  float* orow = dout + ((size_t)b * T_ + q0 + lk * 4) * H_;
#pragma unroll
  for (int hf = 0; hf < 32; ++hf)
#pragma unroll
    for (int r = 0; r < 4; ++r)
      orow[(size_t)r * H_ + hf * 16 + lr] = o[hf][r] * linv[r];
}

// ---------------------------------------------------------------- launch
extern "C" void kernel_launch(void* const* d_in, const int* in_sizes, int n_in,
                              void* d_out, int out_size, void* d_ws, size_t ws_size,
                              hipStream_t stream) {
  const size_t NXE = (size_t)B_ * T_ * C_;   // 16,777,216
  const size_t NWE = (size_t)3 * H_ * C_;    // 786,432
  const size_t NQE = (size_t)B_ * T_ * H_;   // 16,777,216
  const size_t need = (NXE + NWE + 3 * NQE) * sizeof(_Float16);  // 135,790,592 B
  if (ws_size < need) return;  // loud failure (absmax = max|ref|) -> ws too small

  const float* x  = (const float*)d_in[0];
  const float* wq = (const float*)d_in[1];
  const float* wk = (const float*)d_in[2];
  const float* wv = (const float*)d_in[3];

  _Float16* xh  = (_Float16*)d_ws;
  _Float16* wh  = xh + NXE;
  _Float16* qh  = wh + NWE;
  _Float16* kh  = qh + NQE;
  _Float16* vth = kh + NQE;

  cvt_kernel<<<2048, 256, 0, stream>>>((const float4*)x, (const float4*)wq,
                                       (const float4*)wk, (const float4*)wv,
                                       (f16x4*)xh);
  proj_kernel<<<dim3(256, 4, 3), dim3(256), 0, stream>>>(xh, wh, qh, kh, vth);
  attn_kernel<<<1024, 128, 0, stream>>>(qh, kh, vth, (float*)d_out);
}

// Round 4
// 199.359 us; speedup vs baseline: 1.1938x; 1.0143x over previous
//
#include <hip/hip_runtime.h>

#define B_ 128
#define T_ 256
#define C_ 512
#define H_ 512
// softmax scale * log2(e):  (1/sqrt(512)) * 1.44269504
#define CSCALE 0.063763824f

typedef _Float16 f16x8 __attribute__((ext_vector_type(8)));
typedef _Float16 f16x4 __attribute__((ext_vector_type(4)));
typedef float    f32x4 __attribute__((ext_vector_type(4)));

// async global->LDS, 16B per lane; LDS dest must be wave-uniform base (+lane*16)
__device__ __forceinline__ void gld16(const void* gsrc, void* ldst) {
  __builtin_amdgcn_global_load_lds(
      (__attribute__((address_space(1))) void*)gsrc,
      (__attribute__((address_space(3))) void*)ldst, 16, 0, 0);
}

// ---------------------------------------------------------------- convert
__global__ __launch_bounds__(256) void cvt_kernel(
    const float4* __restrict__ x, const float4* __restrict__ wq,
    const float4* __restrict__ wk, const float4* __restrict__ wv,
    f16x4* __restrict__ dst) {
  const int NX = (B_ * T_ * C_) / 4;   // 4,194,304
  const int NW = (H_ * C_) / 4;        // 65,536
  const int total = NX + 3 * NW;
  int gid = blockIdx.x * 256 + threadIdx.x;
  int gsz = gridDim.x * 256;
  for (int i = gid; i < total; i += gsz) {
    float4 f;
    if (i < NX)            f = x[i];
    else if (i < NX + NW)  f = wq[i - NX];
    else if (i < NX + 2*NW) f = wk[i - NX - NW];
    else                   f = wv[i - NX - 2*NW];
    f16x4 u = {(_Float16)f.x, (_Float16)f.y, (_Float16)f.z, (_Float16)f.w};
    dst[i] = u;
  }
}

// ---------------------------------------------------------------- QKV proj
// gemm_bt: out[m][n] = sum_k A[m][k] * W[n][k];  m97 structure (128x128, BK=32)
// z=0 -> q [B*T, H]; z=1 -> k [B*T, H]; z=2 -> v^T [B, H, T]
__global__ __launch_bounds__(256) void proj_kernel(
    const _Float16* __restrict__ xh, const _Float16* __restrict__ wh,
    _Float16* __restrict__ qh, _Float16* __restrict__ kh,
    _Float16* __restrict__ vth) {
  __shared__ _Float16 As[128 * 32];  // 8 KB, row-major [128][32]
  __shared__ _Float16 Bs[128 * 32];  // 8 KB

  const int tid  = threadIdx.x;
  const int lane = tid & 63;
  const int wave = tid >> 6;
  const int lr = lane & 15, lk = lane >> 4;
  const int m0 = blockIdx.x * 128;
  const int n0 = blockIdx.y * 128;
  const int z  = blockIdx.z;
  const _Float16* wz = wh + z * (H_ * C_);

  const int wm = (wave >> 1) * 64;
  const int wn = (wave & 1) * 64;

  f32x4 acc[4][4];
#pragma unroll
  for (int i = 0; i < 4; ++i)
#pragma unroll
    for (int j = 0; j < 4; ++j) acc[i][j] = {0.f, 0.f, 0.f, 0.f};

  // staging: thread t covers row = i*64 + (t>>2), col = (t&3)*8 (8 f16 = 16B)
  const int srow = tid >> 2, scol = (tid & 3) * 8;
  const _Float16* aSrc = xh + (m0 + srow) * C_ + scol;
  const _Float16* bSrc = wz + (n0 + srow) * C_ + scol;

  for (int k0 = 0; k0 < C_; k0 += 32) {
    __syncthreads();  // previous compute done reading LDS
#pragma unroll
    for (int i = 0; i < 2; ++i) {
      gld16((const void*)(aSrc + i * 64 * C_ + k0), (void*)&As[i * 2048 + wave * 512]);
      gld16((const void*)(bSrc + i * 64 * C_ + k0), (void*)&Bs[i * 2048 + wave * 512]);
    }
    __syncthreads();  // staging drained (vmcnt(0) at barrier)

    f16x8 a[4], b[4];
#pragma unroll
    for (int mi = 0; mi < 4; ++mi)
      a[mi] = *(const f16x8*)&As[(wm + mi * 16 + lr) * 32 + lk * 8];
#pragma unroll
    for (int ni = 0; ni < 4; ++ni)
      b[ni] = *(const f16x8*)&Bs[(wn + ni * 16 + lr) * 32 + lk * 8];
#pragma unroll
    for (int mi = 0; mi < 4; ++mi)
#pragma unroll
      for (int ni = 0; ni < 4; ++ni)
        acc[mi][ni] = __builtin_amdgcn_mfma_f32_16x16x32_f16(a[mi], b[ni], acc[mi][ni], 0, 0, 0);
  }

  // epilogue. D layout: col = lane&15, row = (lane>>4)*4 + r   [measured m89/m91]
  if (z < 2) {
    _Float16* out = (z == 0) ? qh : kh;
#pragma unroll
    for (int mi = 0; mi < 4; ++mi) {
      int mbase = m0 + wm + mi * 16 + lk * 4;
#pragma unroll
      for (int ni = 0; ni < 4; ++ni) {
        int n = n0 + wn + ni * 16 + lr;
#pragma unroll
        for (int r = 0; r < 4; ++r)
          out[(mbase + r) * H_ + n] = (_Float16)acc[mi][ni][r];
      }
    }
  } else {
    // v^T[b][h][t]; r=0..3 are consecutive t -> pack 8B store
#pragma unroll
    for (int mi = 0; mi < 4; ++mi) {
      int mbase = m0 + wm + mi * 16 + lk * 4;
      int bb = mbase >> 8, tt = mbase & 255;
#pragma unroll
      for (int ni = 0; ni < 4; ++ni) {
        int n = n0 + wn + ni * 16 + lr;
        f16x4 u = {(_Float16)acc[mi][ni][0], (_Float16)acc[mi][ni][1],
                   (_Float16)acc[mi][ni][2], (_Float16)acc[mi][ni][3]};
        *(f16x4*)&vth[bb * (H_ * T_) + n * T_ + tt] = u;
      }
    }
  }
}

// ---------------------------------------------------------------- attention
// 4-wave block per (batch, 16 q-rows); wave w owns H-quarter w (128 cols).
// QK^T computed as per-wave partial over the H-quarter, summed via a
// conflict-free f32x4 LDS exchange (2 barriers/tile; nkv uniform in block).
// PV + output only on the wave's quarter -> o[8] (32 VGPR) -> ~4 waves/SIMD.
// Grid 2048 = 8 xcd x 16 qw x 16 g; XCD pin: flat%8 == b%8 (K/V L2-local);
// long-first order: qw=15 blocks dispatch first, qw=0 (1 iter) is the tail.
__global__ __launch_bounds__(256, 4) void attn_kernel(
    const _Float16* __restrict__ qh, const _Float16* __restrict__ kh,
    const _Float16* __restrict__ vth, float* __restrict__ dout) {
  __shared__ f32x4 Sx[2][4][64];        // 8 KB exchange, contiguous per instr
  __shared__ _Float16 Ps[4 * 16 * 40];  // 5 KB, per-wave P-transpose scratch

  const int tid  = threadIdx.x;
  const int lane = tid & 63;
  const int wq   = tid >> 6;           // 0..3 = H-quarter
  const int lr = lane & 15, lk = lane >> 4;
  const int flat = blockIdx.x;         // 0..2047
  const int xcd  = flat & 7;
  const int rest = flat >> 3;
  const int qw   = 15 - (rest & 15);   // long-first within each XCD stream
  const int g    = rest >> 4;          // 0..15
  const int b    = xcd + (g << 3);     // batch, pinned to XCD b%8
  const int q0 = qw * 16;
  const int nkv = (qw >> 1) + 1;       // kv tiles of 32
  const int hbase = wq * 128;          // this wave's H-quarter

  // hoist Q fragments (quarter): A-frag row = lr, k covered by (f, lk)
  f16x8 qf[4];
  const _Float16* qrow = qh + ((size_t)b * T_ + q0 + lr) * H_ + hbase;
#pragma unroll
  for (int f = 0; f < 4; ++f) qf[f] = *(const f16x8*)&qrow[f * 32 + lk * 8];

  f32x4 o[8];
#pragma unroll
  for (int i = 0; i < 8; ++i) o[i] = {0.f, 0.f, 0.f, 0.f};
  float m[4], l[4];
#pragma unroll
  for (int r = 0; r < 4; ++r) { m[r] = -1e30f; l[r] = 0.f; }

  const _Float16* kbase = kh + (size_t)b * T_ * H_ + hbase;
  const _Float16* vbase = vth + ((size_t)b * H_ + hbase) * T_;
  _Float16* Pw = &Ps[wq * 640];

  for (int kvt = 0; kvt < nkv; ++kvt) {
    const int kv0 = kvt * 32;

    // ---- QK^T partial over this wave's 128-wide H slice
    f32x4 s0 = {0.f, 0.f, 0.f, 0.f}, s1 = {0.f, 0.f, 0.f, 0.f};
    const _Float16* krow0 = kbase + (size_t)(kv0 + lr) * H_ + lk * 8;
    const _Float16* krow1 = krow0 + 16 * H_;
#pragma unroll
    for (int ks = 0; ks < 4; ++ks) {
      f16x8 b0 = *(const f16x8*)&krow0[ks * 32];
      f16x8 b1 = *(const f16x8*)&krow1[ks * 32];
      s0 = __builtin_amdgcn_mfma_f32_16x16x32_f16(qf[ks], b0, s0, 0, 0, 0);
      s1 = __builtin_amdgcn_mfma_f32_16x16x32_f16(qf[ks], b1, s1, 0, 0, 0);
    }

    // ---- cross-wave sum of partials (full S over H=512)
    Sx[0][wq][lane] = s0;
    Sx[1][wq][lane] = s1;
    __syncthreads();
    {
      f32x4 a0 = Sx[0][0][lane], a1 = Sx[0][1][lane];
      f32x4 a2 = Sx[0][2][lane], a3 = Sx[0][3][lane];
      s0 = (a0 + a1) + (a2 + a3);
      f32x4 c0 = Sx[1][0][lane], c1 = Sx[1][1][lane];
      f32x4 c2 = Sx[1][2][lane], c3 = Sx[1][3][lane];
      s1 = (c0 + c1) + (c2 + c3);
    }
    __syncthreads();  // Sx free for next tile

    // ---- causal mask + row max (rows live in (lk, r); cols across lr)
    float p0[4], p1[4], rm[4];
    const int rowb = q0 + lk * 4;
#pragma unroll
    for (int r = 0; r < 4; ++r) {
      float v0 = (kv0 + lr      > rowb + r) ? -1e30f : s0[r];
      float v1 = (kv0 + 16 + lr > rowb + r) ? -1e30f : s1[r];
      s0[r] = v0; s1[r] = v1;
      rm[r] = fmaxf(v0, v1);
    }
#pragma unroll
    for (int off = 1; off < 16; off <<= 1)
#pragma unroll
      for (int r = 0; r < 4; ++r) rm[r] = fmaxf(rm[r], __shfl_xor(rm[r], off, 64));

    // ---- defer-max (T13): only rescale when max grew > 64 raw (~e^4 headroom)
    bool need = false;
#pragma unroll
    for (int r = 0; r < 4; ++r) need = need || (rm[r] > m[r] + 64.f);
    if (__any(need)) {
#pragma unroll
      for (int r = 0; r < 4; ++r) {
        float mn = fmaxf(m[r], rm[r]);
        float al = __builtin_amdgcn_exp2f((m[r] - mn) * CSCALE);
        m[r] = mn; l[r] *= al;
#pragma unroll
        for (int hf = 0; hf < 8; ++hf) o[hf][r] *= al;
      }
    }

    float rs[4];
#pragma unroll
    for (int r = 0; r < 4; ++r) {
      p0[r] = __builtin_amdgcn_exp2f((s0[r] - m[r]) * CSCALE);
      p1[r] = __builtin_amdgcn_exp2f((s1[r] - m[r]) * CSCALE);
      rs[r] = p0[r] + p1[r];
    }
#pragma unroll
    for (int off = 1; off < 16; off <<= 1)
#pragma unroll
      for (int r = 0; r < 4; ++r) rs[r] += __shfl_xor(rs[r], off, 64);
#pragma unroll
    for (int r = 0; r < 4; ++r) l[r] += rs[r];

    // ---- P transpose through per-wave LDS scratch (wave-private, no barrier)
#pragma unroll
    for (int r = 0; r < 4; ++r) {
      Pw[(lk * 4 + r) * 40 + lr]      = (_Float16)p0[r];
      Pw[(lk * 4 + r) * 40 + 16 + lr] = (_Float16)p1[r];
    }
    f16x8 pa = *(const f16x8*)&Pw[lr * 40 + lk * 8];  // A-frag: row=lr, k=lk*8+j

    // ---- PV on this wave's H-quarter: o[16q x 128h] += P[16x32] * V[32x128]
    const _Float16* vcol = vbase + (size_t)lr * T_ + kv0 + lk * 8;
#pragma unroll
    for (int hf = 0; hf < 8; ++hf) {
      f16x8 vb = *(const f16x8*)&vcol[(size_t)hf * 16 * T_];
      o[hf] = __builtin_amdgcn_mfma_f32_16x16x32_f16(pa, vb, o[hf], 0, 0, 0);
    }
  }

  // ---- normalize + store fp32 (this wave's 128 cols)
  float linv[4];
#pragma unroll
  for (int r = 0; r < 4; ++r) linv[r] = 1.0f / l[r];
  float* orow = dout + ((size_t)b * T_ + q0 + lk * 4) * H_ + hbase;
#pragma unroll
  for (int hf = 0; hf < 8; ++hf)
#pragma unroll
    for (int r = 0; r < 4; ++r)
      orow[(size_t)r * H_ + hf * 16 + lr] = o[hf][r] * linv[r];
}

// ---------------------------------------------------------------- launch
extern "C" void kernel_launch(void* const* d_in, const int* in_sizes, int n_in,
                              void* d_out, int out_size, void* d_ws, size_t ws_size,
                              hipStream_t stream) {
  const size_t NXE = (size_t)B_ * T_ * C_;   // 16,777,216
  const size_t NWE = (size_t)3 * H_ * C_;    // 786,432
  const size_t NQE = (size_t)B_ * T_ * H_;   // 16,777,216
  const size_t need = (NXE + NWE + 3 * NQE) * sizeof(_Float16);  // 135,790,592 B
  if (ws_size < need) return;  // loud failure (absmax = max|ref|) -> ws too small

  const float* x  = (const float*)d_in[0];
  const float* wq = (const float*)d_in[1];
  const float* wk = (const float*)d_in[2];
  const float* wv = (const float*)d_in[3];

  _Float16* xh  = (_Float16*)d_ws;
  _Float16* wh  = xh + NXE;
  _Float16* qh  = wh + NWE;
  _Float16* kh  = qh + NQE;
  _Float16* vth = kh + NQE;

  cvt_kernel<<<2048, 256, 0, stream>>>((const float4*)x, (const float4*)wq,
                                       (const float4*)wk, (const float4*)wv,
                                       (f16x4*)xh);
  proj_kernel<<<dim3(256, 4, 3), dim3(256), 0, stream>>>(xh, wh, qh, kh, vth);
  attn_kernel<<<2048, 256, 0, stream>>>(qh, kh, vth, (float*)d_out);
}

// Round 5
// 175.658 us; speedup vs baseline: 1.3548x; 1.1349x over previous
//
#include <hip/hip_runtime.h>

#define B_ 128
#define T_ 256
#define C_ 512
#define H_ 512
// softmax scale * log2(e):  (1/sqrt(512)) * 1.44269504
#define CSCALE 0.063763824f

typedef _Float16 f16x8 __attribute__((ext_vector_type(8)));
typedef _Float16 f16x4 __attribute__((ext_vector_type(4)));
typedef _Float16 f16x2 __attribute__((ext_vector_type(2)));
typedef float    f32x4 __attribute__((ext_vector_type(4)));
typedef float    f32x16 __attribute__((ext_vector_type(16)));
typedef unsigned int u32;
typedef u32 u32x4 __attribute__((ext_vector_type(4)));

// async global->LDS, 16B per lane; LDS dest must be wave-uniform base (+lane*16)
__device__ __forceinline__ void gld16(const void* gsrc, void* ldst) {
  __builtin_amdgcn_global_load_lds(
      (__attribute__((address_space(1))) void*)gsrc,
      (__attribute__((address_space(3))) void*)ldst, 16, 0, 0);
}

// ---------------------------------------------------------------- convert
__global__ __launch_bounds__(256) void cvt_kernel(
    const float4* __restrict__ x, const float4* __restrict__ wq,
    const float4* __restrict__ wk, const float4* __restrict__ wv,
    f16x4* __restrict__ dst) {
  const int NX = (B_ * T_ * C_) / 4;   // 4,194,304
  const int NW = (H_ * C_) / 4;        // 65,536
  const int total = NX + 3 * NW;
  int gid = blockIdx.x * 256 + threadIdx.x;
  int gsz = gridDim.x * 256;
  for (int i = gid; i < total; i += gsz) {
    float4 f;
    if (i < NX)            f = x[i];
    else if (i < NX + NW)  f = wq[i - NX];
    else if (i < NX + 2*NW) f = wk[i - NX - NW];
    else                   f = wv[i - NX - 2*NW];
    f16x4 u = {(_Float16)f.x, (_Float16)f.y, (_Float16)f.z, (_Float16)f.w};
    dst[i] = u;
  }
}

// ---------------------------------------------------------------- QKV proj
// gemm_bt: out[m][n] = sum_k A[m][k] * W[n][k];  m97 structure (128x128, BK=32)
// z=0 -> q [B*T, H]; z=1 -> k [B*T, H]; z=2 -> v^T [B, H, T]
__global__ __launch_bounds__(256) void proj_kernel(
    const _Float16* __restrict__ xh, const _Float16* __restrict__ wh,
    _Float16* __restrict__ qh, _Float16* __restrict__ kh,
    _Float16* __restrict__ vth) {
  __shared__ _Float16 As[128 * 32];  // 8 KB, row-major [128][32]
  __shared__ _Float16 Bs[128 * 32];  // 8 KB

  const int tid  = threadIdx.x;
  const int lane = tid & 63;
  const int wave = tid >> 6;
  const int lr = lane & 15, lk = lane >> 4;
  const int m0 = blockIdx.x * 128;
  const int n0 = blockIdx.y * 128;
  const int z  = blockIdx.z;
  const _Float16* wz = wh + z * (H_ * C_);

  const int wm = (wave >> 1) * 64;
  const int wn = (wave & 1) * 64;

  f32x4 acc[4][4];
#pragma unroll
  for (int i = 0; i < 4; ++i)
#pragma unroll
    for (int j = 0; j < 4; ++j) acc[i][j] = {0.f, 0.f, 0.f, 0.f};

  // staging: thread t covers row = i*64 + (t>>2), col = (t&3)*8 (8 f16 = 16B)
  const int srow = tid >> 2, scol = (tid & 3) * 8;
  const _Float16* aSrc = xh + (m0 + srow) * C_ + scol;
  const _Float16* bSrc = wz + (n0 + srow) * C_ + scol;

  for (int k0 = 0; k0 < C_; k0 += 32) {
    __syncthreads();  // previous compute done reading LDS
#pragma unroll
    for (int i = 0; i < 2; ++i) {
      gld16((const void*)(aSrc + i * 64 * C_ + k0), (void*)&As[i * 2048 + wave * 512]);
      gld16((const void*)(bSrc + i * 64 * C_ + k0), (void*)&Bs[i * 2048 + wave * 512]);
    }
    __syncthreads();  // staging drained (vmcnt(0) at barrier)

    f16x8 a[4], b[4];
#pragma unroll
    for (int mi = 0; mi < 4; ++mi)
      a[mi] = *(const f16x8*)&As[(wm + mi * 16 + lr) * 32 + lk * 8];
#pragma unroll
    for (int ni = 0; ni < 4; ++ni)
      b[ni] = *(const f16x8*)&Bs[(wn + ni * 16 + lr) * 32 + lk * 8];
#pragma unroll
    for (int mi = 0; mi < 4; ++mi)
#pragma unroll
      for (int ni = 0; ni < 4; ++ni)
        acc[mi][ni] = __builtin_amdgcn_mfma_f32_16x16x32_f16(a[mi], b[ni], acc[mi][ni], 0, 0, 0);
  }

  // epilogue. D layout: col = lane&15, row = (lane>>4)*4 + r   [measured m89/m91]
  if (z < 2) {
    _Float16* out = (z == 0) ? qh : kh;
#pragma unroll
    for (int mi = 0; mi < 4; ++mi) {
      int mbase = m0 + wm + mi * 16 + lk * 4;
#pragma unroll
      for (int ni = 0; ni < 4; ++ni) {
        int n = n0 + wn + ni * 16 + lr;
#pragma unroll
        for (int r = 0; r < 4; ++r)
          out[(mbase + r) * H_ + n] = (_Float16)acc[mi][ni][r];
      }
    }
  } else {
    // v^T[b][h][t]; r=0..3 are consecutive t -> pack 8B store
#pragma unroll
    for (int mi = 0; mi < 4; ++mi) {
      int mbase = m0 + wm + mi * 16 + lk * 4;
      int bb = mbase >> 8, tt = mbase & 255;
#pragma unroll
      for (int ni = 0; ni < 4; ++ni) {
        int n = n0 + wn + ni * 16 + lr;
        f16x4 u = {(_Float16)acc[mi][ni][0], (_Float16)acc[mi][ni][1],
                   (_Float16)acc[mi][ni][2], (_Float16)acc[mi][ni][3]};
        *(f16x4*)&vth[bb * (H_ * T_) + n * T_ + tt] = u;
      }
    }
  }
}

// ---------------------------------------------------------------- attention
// Swapped-QK^T (m214/T12 structure) at 32x32: S^T = mfma(A=K, B=Q) so each
// lane owns ONE q-row (col = lane&31) and kv is lane-local -> softmax is
// in-register (15 fmax + ONE shfl_xor(32)); m,l are per-lane scalars; the
// P-transpose LDS round-trip is replaced by pack + 8 shfl + cndmask.
// H=512 forces an H-split: 4 waves each own a 128-col H-quarter; QK^T
// partials summed via double-buffered conflict-free LDS exchange (1 barrier
// per kv-tile). PV B-frag from packed P; A-frags (K rows, V^T rows) are
// 16B-contiguous direct-global (L2-resident via XCD pin).
// Grid 1024 = 8 xcd x 8 qb x 16 g; long-first (qb=7 dispatches first).
__global__ __launch_bounds__(256, 2) void attn_kernel(
    const _Float16* __restrict__ qh, const _Float16* __restrict__ kh,
    const _Float16* __restrict__ vth, float* __restrict__ dout) {
  __shared__ f32x4 Ex[2][4][4][64];  // [buf][wave][chunk][lane] = 32 KB

  const int tid  = threadIdx.x;
  const int lane = tid & 63;
  const int wq   = tid >> 6;          // 0..3 = H-quarter
  const int lq   = lane & 31;         // this lane's q row (within tile)
  const int hi   = lane >> 5;
  const int flat = blockIdx.x;        // 0..1023
  const int xcd  = flat & 7;
  const int rest = flat >> 3;
  const int qb   = 7 - (rest & 7);    // long-first within each XCD stream
  const int g    = rest >> 3;         // 0..15
  const int b    = xcd + (g << 3);    // batch, pinned to XCD b%8
  const int q0   = qb * 32;
  const int nkv  = qb + 1;            // kv tiles of 32
  const int hbase = wq * 128;
  const int qg   = q0 + lq;           // global q row for this lane

  // Q as B-operand frags: B[k=h][col=q]; lane holds Q[qg][hbase+ks*16+hi*8+j]
  f16x8 qf[8];
  const _Float16* qp = qh + ((size_t)b * T_ + qg) * H_ + hbase + hi * 8;
#pragma unroll
  for (int ks = 0; ks < 8; ++ks) qf[ks] = *(const f16x8*)&qp[ks * 16];

  f32x16 ot[4];  // O^T quarter: [ht] -> rows ht*32+(reg&3)+8*(reg>>2)+4hi, col q
#pragma unroll
  for (int i = 0; i < 4; ++i) ot[i] = {};
  float m_ = -1e30f, l_ = 0.f;

  const _Float16* kp = kh  + ((size_t)b * T_ + lq) * H_ + hbase + hi * 8;
  const _Float16* vp = vth + ((size_t)b * H_ + hbase + lq) * T_ + hi * 8;

  for (int kvt = 0; kvt < nkv; ++kvt) {
    const int kv0 = kvt * 32;

    // ---- QK^T partial over this wave's 128 H-cols: A=K[32kv x 16h] x8
    f16x8 kf[8];
#pragma unroll
    for (int ks = 0; ks < 8; ++ks)
      kf[ks] = *(const f16x8*)&kp[(size_t)kv0 * H_ + ks * 16];
    f32x16 st = {};
#pragma unroll
    for (int ks = 0; ks < 8; ++ks)
      st = __builtin_amdgcn_mfma_f32_32x32x16_f16(kf[ks], qf[ks], st, 0, 0, 0);

    // ---- cross-wave sum (double-buffered, ONE barrier per tile)
    const int buf = kvt & 1;
#pragma unroll
    for (int c = 0; c < 4; ++c) {
      f32x4 w4 = {st[c*4+0], st[c*4+1], st[c*4+2], st[c*4+3]};
      Ex[buf][wq][c][lane] = w4;
    }
    __syncthreads();
#pragma unroll
    for (int ow = 0; ow < 4; ++ow) {
      if (ow == wq) continue;  // wave-uniform
#pragma unroll
      for (int c = 0; c < 4; ++c) {
        f32x4 r4 = Ex[buf][ow][c][lane];
        st[c*4+0] += r4[0]; st[c*4+1] += r4[1];
        st[c*4+2] += r4[2]; st[c*4+3] += r4[3];
      }
    }

    // ---- causal mask + in-register row softmax (q = lane-local)
    float p[16], rm = -1e30f;
    const int kvb = kv0 + 4 * hi;
#pragma unroll
    for (int r = 0; r < 16; ++r) {
      int kvg = kvb + (r & 3) + 8 * (r >> 2);
      float v = (kvg > qg) ? -1e30f : st[r];
      p[r] = v;
      rm = fmaxf(rm, v);
    }
    rm = fmaxf(rm, __shfl_xor(rm, 32, 64));  // partner holds other 16 kv

    // defer-max (T13): rescale only when max grew > 64 raw (~e^4 headroom)
    if (__any((int)(rm > m_ + 64.f))) {
      float mn = fmaxf(m_, rm);
      float al = __builtin_amdgcn_exp2f((m_ - mn) * CSCALE);
      m_ = mn; l_ *= al;
#pragma unroll
      for (int i = 0; i < 4; ++i)
#pragma unroll
        for (int e = 0; e < 16; ++e) ot[i][e] *= al;
    }
    float rs = 0.f;
#pragma unroll
    for (int r = 0; r < 16; ++r) {
      p[r] = __builtin_amdgcn_exp2f((p[r] - m_) * CSCALE);
      rs += p[r];
    }
    rs += __shfl_xor(rs, 32, 64);
    l_ += rs;

    // ---- P -> f16 pack + partner exchange -> PV B-frags (no LDS)
    // w[i] holds kv pair; kv(w[i]) = {0,1},{2,3},{8,9},{10,11},{16,17},
    // {18,19},{24,25},{26,27} each +4*hi
    u32 w[8], sw[8];
#pragma unroll
    for (int i = 0; i < 8; ++i) {
      f16x2 h2; h2[0] = (_Float16)p[2*i]; h2[1] = (_Float16)p[2*i+1];
      w[i] = __builtin_bit_cast(u32, h2);
    }
#pragma unroll
    for (int i = 0; i < 8; ++i) sw[i] = (u32)__shfl_xor((int)w[i], 32, 64);
    // B0: k=kv 0..15 -> lane needs kv {8hi..8hi+7}; B1: kv 16..31
    u32x4 t0 = { hi ? sw[2] : w[0],  hi ? sw[3] : w[1],
                 hi ? w[2]  : sw[0], hi ? w[3]  : sw[1] };
    u32x4 t1 = { hi ? sw[6] : w[4],  hi ? sw[7] : w[5],
                 hi ? w[6]  : sw[4], hi ? w[7]  : sw[5] };
    f16x8 pb0 = __builtin_bit_cast(f16x8, t0);
    f16x8 pb1 = __builtin_bit_cast(f16x8, t1);

    // ---- PV on H-quarter: O^T[32h x 32q] += V^T[32h x 32kv] * P^T
#pragma unroll
    for (int ht = 0; ht < 4; ++ht) {
      f16x8 va0 = *(const f16x8*)&vp[(size_t)(ht * 32) * T_ + kv0];
      f16x8 va1 = *(const f16x8*)&vp[(size_t)(ht * 32) * T_ + kv0 + 16];
      ot[ht] = __builtin_amdgcn_mfma_f32_32x32x16_f16(va0, pb0, ot[ht], 0, 0, 0);
      ot[ht] = __builtin_amdgcn_mfma_f32_32x32x16_f16(va1, pb1, ot[ht], 0, 0, 0);
    }
  }

  // ---- normalize + store fp32 (lane's q row, wave's 128 H-cols)
  float li = 1.0f / l_;
  float* op = dout + ((size_t)b * T_ + qg) * H_ + hbase + 4 * hi;
#pragma unroll
  for (int ht = 0; ht < 4; ++ht)
#pragma unroll
    for (int rq = 0; rq < 4; ++rq) {
      f32x4 v4 = {ot[ht][rq*4+0] * li, ot[ht][rq*4+1] * li,
                  ot[ht][rq*4+2] * li, ot[ht][rq*4+3] * li};
      *(f32x4*)&op[ht * 32 + rq * 8] = v4;
    }
}

// ---------------------------------------------------------------- launch
extern "C" void kernel_launch(void* const* d_in, const int* in_sizes, int n_in,
                              void* d_out, int out_size, void* d_ws, size_t ws_size,
                              hipStream_t stream) {
  const size_t NXE = (size_t)B_ * T_ * C_;   // 16,777,216
  const size_t NWE = (size_t)3 * H_ * C_;    // 786,432
  const size_t NQE = (size_t)B_ * T_ * H_;   // 16,777,216
  const size_t need = (NXE + NWE + 3 * NQE) * sizeof(_Float16);  // 135,790,592 B
  if (ws_size < need) return;  // loud failure (absmax = max|ref|) -> ws too small

  const float* x  = (const float*)d_in[0];
  const float* wq = (const float*)d_in[1];
  const float* wk = (const float*)d_in[2];
  const float* wv = (const float*)d_in[3];

  _Float16* xh  = (_Float16*)d_ws;
  _Float16* wh  = xh + NXE;
  _Float16* qh  = wh + NWE;
  _Float16* kh  = qh + NQE;
  _Float16* vth = kh + NQE;

  cvt_kernel<<<2048, 256, 0, stream>>>((const float4*)x, (const float4*)wq,
                                       (const float4*)wk, (const float4*)wv,
                                       (f16x4*)xh);
  proj_kernel<<<dim3(256, 4, 3), dim3(256), 0, stream>>>(xh, wh, qh, kh, vth);
  attn_kernel<<<1024, 256, 0, stream>>>(qh, kh, vth, (float*)d_out);
}

// Round 6
// 171.935 us; speedup vs baseline: 1.3842x; 1.0216x over previous
//
#include <hip/hip_runtime.h>

#define B_ 128
#define T_ 256
#define C_ 512
#define H_ 512
// softmax scale * log2(e):  (1/sqrt(512)) * 1.44269504
#define CSCALE 0.063763824f

typedef _Float16 f16x8 __attribute__((ext_vector_type(8)));
typedef _Float16 f16x4 __attribute__((ext_vector_type(4)));
typedef _Float16 f16x2 __attribute__((ext_vector_type(2)));
typedef float    f32x4 __attribute__((ext_vector_type(4)));
typedef float    f32x16 __attribute__((ext_vector_type(16)));
typedef unsigned int u32;
typedef u32 u32x4 __attribute__((ext_vector_type(4)));

// async global->LDS, 16B per lane; LDS dest must be wave-uniform base (+lane*16)
__device__ __forceinline__ void gld16(const void* gsrc, void* ldst) {
  __builtin_amdgcn_global_load_lds(
      (__attribute__((address_space(1))) void*)gsrc,
      (__attribute__((address_space(3))) void*)ldst, 16, 0, 0);
}

// ---------------------------------------------------------------- convert
__global__ __launch_bounds__(256) void cvt_kernel(
    const float4* __restrict__ x, const float4* __restrict__ wq,
    const float4* __restrict__ wk, const float4* __restrict__ wv,
    f16x4* __restrict__ dst) {
  const int NX = (B_ * T_ * C_) / 4;   // 4,194,304
  const int NW = (H_ * C_) / 4;        // 65,536
  const int total = NX + 3 * NW;
  int gid = blockIdx.x * 256 + threadIdx.x;
  int gsz = gridDim.x * 256;
  for (int i = gid; i < total; i += gsz) {
    float4 f;
    if (i < NX)            f = x[i];
    else if (i < NX + NW)  f = wq[i - NX];
    else if (i < NX + 2*NW) f = wk[i - NX - NW];
    else                   f = wv[i - NX - 2*NW];
    f16x4 u = {(_Float16)f.x, (_Float16)f.y, (_Float16)f.z, (_Float16)f.w};
    dst[i] = u;
  }
}

// ---------------------------------------------------------------- QKV proj
// 256x256 tile, BK=64, 8 waves (2Mx4N), 8-phase K-loop with counted vmcnt(4)
// (T3+T4), conflict-free subtile LDS (T2 via pre-permuted gld16 sources),
// setprio around MFMA (T5). K-split half-tiles (A_k0,B_k0,A_k1,B_k1; 16 KB
// each) staged 4 phases ahead into the other buffer -> race-free dbuf and
// loads stay in flight across barriers (never vmcnt(0) in the loop).
// LDS subtile = 16 rows x 32 cols f16 = 1 KB; physical 16B-slot = reader
// lane id -> every ds_read_b128 is base + lane*16 (zero bank conflicts).
// z=0 -> q [B*T, H]; z=1 -> k; z=2 -> v^T [B, H, T].
__global__ __launch_bounds__(512, 2) void proj_kernel(
    const _Float16* __restrict__ xh, const _Float16* __restrict__ wh,
    _Float16* __restrict__ qh, _Float16* __restrict__ kh,
    _Float16* __restrict__ vth) {
  __shared__ _Float16 L[65536];  // 128 KB: [buf][A 16384 f16 | B 16384 f16]

  const int tid  = threadIdx.x;
  const int lane = tid & 63;
  const int wave = tid >> 6;          // 0..7
  const int lr = lane & 15, lk = lane >> 4;
  const int lane8 = lane * 8;         // f16 offset of this lane's 16B slot
  const int wr = wave >> 2, wc = wave & 3;
  const int m0 = blockIdx.x * 256;
  const int n0 = blockIdx.y * 256;
  const int z  = blockIdx.z;
  const _Float16* wz = wh + z * (H_ * C_);

  // stage source mapping (slot S = ii*512 + tid):
  // row = (ii*8 + wave)*16 + lr, col(within 32-col half) = lk*8
  const int srow = wave * 16 + lr;    // ii=0 row; ii=1 adds 128
  const int scol = lk * 8;
  const _Float16* aS = xh + (size_t)(m0 + srow) * C_ + scol;
  const _Float16* bS = wz + (size_t)(n0 + srow) * C_ + scol;

  f32x4 acc[8][4];
#pragma unroll
  for (int i = 0; i < 8; ++i)
#pragma unroll
    for (int j = 0; j < 4; ++j) acc[i][j] = {0.f, 0.f, 0.f, 0.f};
  f16x8 af[4], bf[4];

  // ---- prologue: tile 0 -> buf0 in half order A_k0, B_k0, A_k1, B_k1
  gld16(aS,               &L[(wave) * 512]);
  gld16(aS + 65536,       &L[(8 + wave) * 512]);
  gld16(bS,               &L[16384 + (wave) * 512]);
  gld16(bS + 65536,       &L[16384 + (8 + wave) * 512]);
  gld16(aS + 32,          &L[(16 + wave) * 512]);
  gld16(aS + 65536 + 32,  &L[(16 + 8 + wave) * 512]);
  gld16(bS + 32,          &L[16384 + (16 + wave) * 512]);
  gld16(bS + 65536 + 32,  &L[16384 + (16 + 8 + wave) * 512]);
  asm volatile("s_waitcnt vmcnt(4)" ::: "memory");  // k0 halves landed
  __builtin_amdgcn_s_barrier();

// one phase: ds_read quadrant frags | stage one half-tile | barrier |
// 16 MFMA (setprio) | [vmcnt(4) at odd phases] | barrier
#define PH(BUF, MH, KH, STK, SKK, SBUF, SB, VM) do {                          \
    if ((MH) == 0) {                                                           \
      _Pragma("unroll") for (int ni = 0; ni < 4; ++ni)                         \
        bf[ni] = *(const f16x8*)&L[(BUF) * 32768 + 16384 +                     \
                                   ((KH) * 16 + wc * 4 + ni) * 512 + lane8];   \
    }                                                                          \
    _Pragma("unroll") for (int q = 0; q < 4; ++q)                              \
      af[q] = *(const f16x8*)&L[(BUF) * 32768 +                                \
                                ((KH) * 16 + wr * 8 + (MH) * 4 + q) * 512 +    \
                                lane8];                                        \
    {                                                                          \
      const _Float16* s_ = (SB) ? bS : aS;                                     \
      const int db_ = (SBUF) * 32768 + ((SB) ? 16384 : 0);                     \
      gld16(s_ + (STK) + (SKK) * 32,                                           \
            &L[db_ + ((SKK) * 16 + wave) * 512]);                              \
      gld16(s_ + 65536 + (STK) + (SKK) * 32,                                   \
            &L[db_ + ((SKK) * 16 + 8 + wave) * 512]);                          \
    }                                                                          \
    __builtin_amdgcn_s_barrier();                                              \
    __builtin_amdgcn_s_setprio(1);                                             \
    _Pragma("unroll") for (int q = 0; q < 4; ++q)                              \
      _Pragma("unroll") for (int ni = 0; ni < 4; ++ni)                         \
        acc[(MH) * 4 + q][ni] = __builtin_amdgcn_mfma_f32_16x16x32_f16(        \
            af[q], bf[ni], acc[(MH) * 4 + q][ni], 0, 0, 0);                    \
    __builtin_amdgcn_s_setprio(0);                                             \
    if (VM) asm volatile("s_waitcnt vmcnt(4)" ::: "memory");                   \
    __builtin_amdgcn_s_barrier();                                              \
  } while (0)

#pragma unroll 1
  for (int it = 0; it < 4; ++it) {
    const int k1 = (2 * it + 1) * 64;                    // tile t1 -> buf1
    const int k2 = (2 * it + 2 < 8 ? 2 * it + 2 : 7) * 64;  // t2 -> buf0 (clamped)
    PH(0, 0, 0, k1, 0, 1, 0, 0);  // P0: compute buf0 (kh0,mh0); stage A_k0(t1)
    PH(0, 1, 0, k1, 0, 1, 1, 1);  // P1: (kh0,mh1); B_k0(t1); vmcnt(4)
    PH(0, 0, 1, k1, 1, 1, 0, 0);  // P2: (kh1,mh0); A_k1(t1)
    PH(0, 1, 1, k1, 1, 1, 1, 1);  // P3: (kh1,mh1); B_k1(t1); vmcnt(4)
    PH(1, 0, 0, k2, 0, 0, 0, 0);  // P4: compute buf1; stage A_k0(t2)
    PH(1, 1, 0, k2, 0, 0, 1, 1);  // P5: B_k0(t2); vmcnt(4)
    PH(1, 0, 1, k2, 1, 0, 0, 0);  // P6: A_k1(t2)
    PH(1, 1, 1, k2, 1, 0, 1, 1);  // P7: B_k1(t2); vmcnt(4)
  }
#undef PH

  // ---- epilogue. D layout: col = lane&15, row = (lane>>4)*4 + r  [m89/m91]
  if (z < 2) {
    _Float16* out = (z == 0) ? qh : kh;
#pragma unroll
    for (int mi = 0; mi < 8; ++mi) {
      int mg = m0 + wr * 128 + mi * 16 + lk * 4;
#pragma unroll
      for (int ni = 0; ni < 4; ++ni) {
        int n = n0 + wc * 64 + ni * 16 + lr;
#pragma unroll
        for (int r = 0; r < 4; ++r)
          out[(size_t)(mg + r) * H_ + n] = (_Float16)acc[mi][ni][r];
      }
    }
  } else {
    // v^T[b][h][t]; 256-row M-tile == one batch (T=256); r = consecutive t
    int bb = m0 >> 8;
#pragma unroll
    for (int mi = 0; mi < 8; ++mi) {
      int ttb = wr * 128 + mi * 16 + lk * 4;
#pragma unroll
      for (int ni = 0; ni < 4; ++ni) {
        int n = n0 + wc * 64 + ni * 16 + lr;
        f16x4 u = {(_Float16)acc[mi][ni][0], (_Float16)acc[mi][ni][1],
                   (_Float16)acc[mi][ni][2], (_Float16)acc[mi][ni][3]};
        *(f16x4*)&vth[(size_t)bb * (H_ * T_) + (size_t)n * T_ + ttb] = u;
      }
    }
  }
}

// ---------------------------------------------------------------- attention
// Swapped-QK^T (m214/T12 structure) at 32x32: S^T = mfma(A=K, B=Q) so each
// lane owns ONE q-row (col = lane&31) and kv is lane-local -> softmax is
// in-register (15 fmax + ONE shfl_xor(32)); m,l are per-lane scalars; the
// P-transpose LDS round-trip is replaced by pack + 8 shfl + cndmask.
// H=512 forces an H-split: 4 waves each own a 128-col H-quarter; QK^T
// partials summed via double-buffered conflict-free LDS exchange (1 barrier
// per kv-tile). PV B-frag from packed P; A-frags (K rows, V^T rows) are
// 16B-contiguous direct-global (L2-resident via XCD pin).
// Grid 1024 = 8 xcd x 8 qb x 16 g; long-first (qb=7 dispatches first).
__global__ __launch_bounds__(256, 2) void attn_kernel(
    const _Float16* __restrict__ qh, const _Float16* __restrict__ kh,
    const _Float16* __restrict__ vth, float* __restrict__ dout) {
  __shared__ f32x4 Ex[2][4][4][64];  // [buf][wave][chunk][lane] = 32 KB

  const int tid  = threadIdx.x;
  const int lane = tid & 63;
  const int wq   = tid >> 6;          // 0..3 = H-quarter
  const int lq   = lane & 31;         // this lane's q row (within tile)
  const int hi   = lane >> 5;
  const int flat = blockIdx.x;        // 0..1023
  const int xcd  = flat & 7;
  const int rest = flat >> 3;
  const int qb   = 7 - (rest & 7);    // long-first within each XCD stream
  const int g    = rest >> 3;         // 0..15
  const int b    = xcd + (g << 3);    // batch, pinned to XCD b%8
  const int q0   = qb * 32;
  const int nkv  = qb + 1;            // kv tiles of 32
  const int hbase = wq * 128;
  const int qg   = q0 + lq;           // global q row for this lane

  // Q as B-operand frags: B[k=h][col=q]; lane holds Q[qg][hbase+ks*16+hi*8+j]
  f16x8 qf[8];
  const _Float16* qp = qh + ((size_t)b * T_ + qg) * H_ + hbase + hi * 8;
#pragma unroll
  for (int ks = 0; ks < 8; ++ks) qf[ks] = *(const f16x8*)&qp[ks * 16];

  f32x16 ot[4];  // O^T quarter: [ht] -> rows ht*32+(reg&3)+8*(reg>>2)+4hi, col q
#pragma unroll
  for (int i = 0; i < 4; ++i) ot[i] = {};
  float m_ = -1e30f, l_ = 0.f;

  const _Float16* kp = kh  + ((size_t)b * T_ + lq) * H_ + hbase + hi * 8;
  const _Float16* vp = vth + ((size_t)b * H_ + hbase + lq) * T_ + hi * 8;

  for (int kvt = 0; kvt < nkv; ++kvt) {
    const int kv0 = kvt * 32;

    // ---- QK^T partial over this wave's 128 H-cols: A=K[32kv x 16h] x8
    f16x8 kf[8];
#pragma unroll
    for (int ks = 0; ks < 8; ++ks)
      kf[ks] = *(const f16x8*)&kp[(size_t)kv0 * H_ + ks * 16];
    f32x16 st = {};
#pragma unroll
    for (int ks = 0; ks < 8; ++ks)
      st = __builtin_amdgcn_mfma_f32_32x32x16_f16(kf[ks], qf[ks], st, 0, 0, 0);

    // ---- cross-wave sum (double-buffered, ONE barrier per tile)
    const int buf = kvt & 1;
#pragma unroll
    for (int c = 0; c < 4; ++c) {
      f32x4 w4 = {st[c*4+0], st[c*4+1], st[c*4+2], st[c*4+3]};
      Ex[buf][wq][c][lane] = w4;
    }
    __syncthreads();
#pragma unroll
    for (int ow = 0; ow < 4; ++ow) {
      if (ow == wq) continue;  // wave-uniform
#pragma unroll
      for (int c = 0; c < 4; ++c) {
        f32x4 r4 = Ex[buf][ow][c][lane];
        st[c*4+0] += r4[0]; st[c*4+1] += r4[1];
        st[c*4+2] += r4[2]; st[c*4+3] += r4[3];
      }
    }

    // ---- causal mask + in-register row softmax (q = lane-local)
    float p[16], rm = -1e30f;
    const int kvb = kv0 + 4 * hi;
#pragma unroll
    for (int r = 0; r < 16; ++r) {
      int kvg = kvb + (r & 3) + 8 * (r >> 2);
      float v = (kvg > qg) ? -1e30f : st[r];
      p[r] = v;
      rm = fmaxf(rm, v);
    }
    rm = fmaxf(rm, __shfl_xor(rm, 32, 64));  // partner holds other 16 kv

    // defer-max (T13): rescale only when max grew > 64 raw (~e^4 headroom)
    if (__any((int)(rm > m_ + 64.f))) {
      float mn = fmaxf(m_, rm);
      float al = __builtin_amdgcn_exp2f((m_ - mn) * CSCALE);
      m_ = mn; l_ *= al;
#pragma unroll
      for (int i = 0; i < 4; ++i)
#pragma unroll
        for (int e = 0; e < 16; ++e) ot[i][e] *= al;
    }
    float rs = 0.f;
#pragma unroll
    for (int r = 0; r < 16; ++r) {
      p[r] = __builtin_amdgcn_exp2f((p[r] - m_) * CSCALE);
      rs += p[r];
    }
    rs += __shfl_xor(rs, 32, 64);
    l_ += rs;

    // ---- P -> f16 pack + partner exchange -> PV B-frags (no LDS)
    u32 w[8], sw[8];
#pragma unroll
    for (int i = 0; i < 8; ++i) {
      f16x2 h2; h2[0] = (_Float16)p[2*i]; h2[1] = (_Float16)p[2*i+1];
      w[i] = __builtin_bit_cast(u32, h2);
    }
#pragma unroll
    for (int i = 0; i < 8; ++i) sw[i] = (u32)__shfl_xor((int)w[i], 32, 64);
    u32x4 t0 = { hi ? sw[2] : w[0],  hi ? sw[3] : w[1],
                 hi ? w[2]  : sw[0], hi ? w[3]  : sw[1] };
    u32x4 t1 = { hi ? sw[6] : w[4],  hi ? sw[7] : w[5],
                 hi ? w[6]  : sw[4], hi ? w[7]  : sw[5] };
    f16x8 pb0 = __builtin_bit_cast(f16x8, t0);
    f16x8 pb1 = __builtin_bit_cast(f16x8, t1);

    // ---- PV on H-quarter: O^T[32h x 32q] += V^T[32h x 32kv] * P^T
#pragma unroll
    for (int ht = 0; ht < 4; ++ht) {
      f16x8 va0 = *(const f16x8*)&vp[(size_t)(ht * 32) * T_ + kv0];
      f16x8 va1 = *(const f16x8*)&vp[(size_t)(ht * 32) * T_ + kv0 + 16];
      ot[ht] = __builtin_amdgcn_mfma_f32_32x32x16_f16(va0, pb0, ot[ht], 0, 0, 0);
      ot[ht] = __builtin_amdgcn_mfma_f32_32x32x16_f16(va1, pb1, ot[ht], 0, 0, 0);
    }
  }

  // ---- normalize + store fp32 (lane's q row, wave's 128 H-cols)
  float li = 1.0f / l_;
  float* op = dout + ((size_t)b * T_ + qg) * H_ + hbase + 4 * hi;
#pragma unroll
  for (int ht = 0; ht < 4; ++ht)
#pragma unroll
    for (int rq = 0; rq < 4; ++rq) {
      f32x4 v4 = {ot[ht][rq*4+0] * li, ot[ht][rq*4+1] * li,
                  ot[ht][rq*4+2] * li, ot[ht][rq*4+3] * li};
      *(f32x4*)&op[ht * 32 + rq * 8] = v4;
    }
}

// ---------------------------------------------------------------- launch
extern "C" void kernel_launch(void* const* d_in, const int* in_sizes, int n_in,
                              void* d_out, int out_size, void* d_ws, size_t ws_size,
                              hipStream_t stream) {
  const size_t NXE = (size_t)B_ * T_ * C_;   // 16,777,216
  const size_t NWE = (size_t)3 * H_ * C_;    // 786,432
  const size_t NQE = (size_t)B_ * T_ * H_;   // 16,777,216
  const size_t need = (NXE + NWE + 3 * NQE) * sizeof(_Float16);  // 135,790,592 B
  if (ws_size < need) return;  // loud failure (absmax = max|ref|) -> ws too small

  const float* x  = (const float*)d_in[0];
  const float* wq = (const float*)d_in[1];
  const float* wk = (const float*)d_in[2];
  const float* wv = (const float*)d_in[3];

  _Float16* xh  = (_Float16*)d_ws;
  _Float16* wh  = xh + NXE;
  _Float16* qh  = wh + NWE;
  _Float16* kh  = qh + NQE;
  _Float16* vth = kh + NQE;

  cvt_kernel<<<2048, 256, 0, stream>>>((const float4*)x, (const float4*)wq,
                                       (const float4*)wk, (const float4*)wv,
                                       (f16x4*)xh);
  proj_kernel<<<dim3(128, 2, 3), 512, 0, stream>>>(xh, wh, qh, kh, vth);
  attn_kernel<<<1024, 256, 0, stream>>>(qh, kh, vth, (float*)d_out);
}